// Round 2
// baseline (434.800 us; speedup 1.0000x reference)
//
#include <hip/hip_runtime.h>
#include <stdint.h>

#define B_ 4
#define L_ 2048
#define H_ 8
#define E_ 64
#define S_ 2048
#define QT 16

typedef __bf16 bf16x8 __attribute__((ext_vector_type(8)));
typedef float f32x4 __attribute__((ext_vector_type(4)));
typedef unsigned short u16;
typedef u16 u16x4 __attribute__((ext_vector_type(4)));

__device__ __forceinline__ u16 f32_to_bf16(float f) {
  union { float f; uint32_t u; } x;
  x.f = f;
  uint32_t u = x.u;
  return (u16)((u + 0x7FFFu + ((u >> 16) & 1u)) >> 16);
}

__device__ __forceinline__ float bf16_to_f32(u16 h) {
  union { uint32_t u; float f; } x;
  x.u = ((uint32_t)h) << 16;
  return x.f;
}

// q' = bf16(q * tau[b] / sqrt(E)), k' = bf16(k), delta' = delta / sqrt(E)
__global__ __launch_bounds__(256) void prep_qkd(
    const float* __restrict__ q, const float* __restrict__ k,
    const float* __restrict__ tau, const float* __restrict__ delta,
    u16* __restrict__ qb, u16* __restrict__ kb, float* __restrict__ dl) {
  int idx = blockIdx.x * 256 + threadIdx.x;  // 0 .. 1048575
  int i4 = idx * 4;
  int b = i4 >> 20;  // L_*H_*E_ = 2^20 per batch
  float ts = tau[b] * 0.125f;
  f32x4 qv = *(const f32x4*)(q + i4);
  f32x4 kv = *(const f32x4*)(k + i4);
  u16x4 qs, ks;
#pragma unroll
  for (int j = 0; j < 4; ++j) {
    qs[j] = f32_to_bf16(qv[j] * ts);
    ks[j] = f32_to_bf16(kv[j]);
  }
  *(u16x4*)(qb + i4) = qs;
  *(u16x4*)(kb + i4) = ks;
  if (idx < (B_ * S_) / 4) {
    f32x4 dv = *(const f32x4*)(delta + i4);
    f32x4 ds = {dv[0] * 0.125f, dv[1] * 0.125f, dv[2] * 0.125f, dv[3] * 0.125f};
    *(f32x4*)(dl + i4) = ds;
  }
}

// V [B,S,H,E] f32 -> V' [B,H,E,S] bf16 (tiled transpose)
__global__ __launch_bounds__(256) void prep_v(const float* __restrict__ v,
                                              u16* __restrict__ vb) {
  __shared__ float t[32][33];
  int bid = blockIdx.x;
  int et = bid & 1;
  int st = (bid >> 1) & 63;
  int h = (bid >> 7) & 7;
  int b = bid >> 10;
  int tx = threadIdx.x & 31;
  int ty = threadIdx.x >> 5;  // 0..7
#pragma unroll
  for (int k2 = 0; k2 < 4; ++k2) {
    int s = st * 32 + ty + 8 * k2;
    int e = et * 32 + tx;
    t[ty + 8 * k2][tx] = v[(((size_t)b * S_ + s) * H_ + h) * E_ + e];
  }
  __syncthreads();
#pragma unroll
  for (int k2 = 0; k2 < 4; ++k2) {
    int e = et * 32 + ty + 8 * k2;
    int s = st * 32 + tx;
    vb[(((size_t)b * H_ + h) * E_ + e) * S_ + s] = f32_to_bf16(t[tx][ty + 8 * k2]);
  }
}

// Fused two-pass attention. One wave = 16 q-rows of one (b,h). 4 waves/WG.
// Pass A: row sums of exp(logit) (no max subtraction -- logits bounded ~7.5).
// Pass B: recompute logits, write normalized a (coalesced f32x4), PV via MFMA.
__global__ __launch_bounds__(256, 4) void attn_fused(
    const u16* __restrict__ qb, const u16* __restrict__ kb,
    const u16* __restrict__ vb, const float* __restrict__ dl,
    float* __restrict__ out, float* __restrict__ oa) {
  // per-wave p tile: 16 rows x 32 cols bf16, row stride 40 halves (80 B) to
  // stagger banks; 16B-aligned for ds_read_b128.
  __shared__ __align__(16) u16 pt[4][16][40];
  __shared__ float zsh[4][16];

  int bid = blockIdx.x;
  // XCD swizzle: 1024 WGs, 8 XCDs -> 128-contiguous chunk per XCD
  int swz = (bid & 7) * 128 + (bid >> 3);
  int tid = threadIdx.x;
  int lane = tid & 63;
  int wave = tid >> 6;
  int t = swz * 4 + wave;  // 0..4095 wave-tasks
  int b = t >> 10;
  int h = (t >> 7) & 7;
  int qt = t & 127;
  int m0 = qt * QT;
  int l15 = lane & 15;
  int l4 = lane >> 4;

  const float LOG2E = 1.44269504088896f;

  // Q fragment (A): row = lane&15, k(e) = 8*(lane>>4)+j; two K=32 halves
  bf16x8 qa0, qa1;
  {
    const u16* qp = qb + (((size_t)b * L_ + (m0 + l15)) * H_ + h) * E_ + 8 * l4;
    qa0 = *(const bf16x8*)(qp);
    qa1 = *(const bf16x8*)(qp + 32);
  }

  const u16* kbase = kb + (((size_t)b * S_ + l15) * H_ + h) * E_ + 8 * l4;
  const float* dbase = dl + b * S_ + l15;

  // ---- Pass A: row sums of exp ----
  float sums[4] = {0.f, 0.f, 0.f, 0.f};
#pragma unroll 4
  for (int c = 0; c < 128; ++c) {
    const u16* kp = kbase + (size_t)c * (16 * H_ * E_);
    f32x4 acc = {0.f, 0.f, 0.f, 0.f};
    acc = __builtin_amdgcn_mfma_f32_16x16x32_bf16(qa0, *(const bf16x8*)(kp), acc, 0, 0, 0);
    acc = __builtin_amdgcn_mfma_f32_16x16x32_bf16(qa1, *(const bf16x8*)(kp + 32), acc, 0, 0, 0);
    float d = dbase[c * 16];
#pragma unroll
    for (int r = 0; r < 4; ++r)
      sums[r] += __builtin_amdgcn_exp2f((acc[r] + d) * LOG2E);
  }
#pragma unroll
  for (int r = 0; r < 4; ++r) {
    sums[r] += __shfl_xor(sums[r], 1, 64);
    sums[r] += __shfl_xor(sums[r], 2, 64);
    sums[r] += __shfl_xor(sums[r], 4, 64);
    sums[r] += __shfl_xor(sums[r], 8, 64);
  }
  float zinv[4];
#pragma unroll
  for (int r = 0; r < 4; ++r) zinv[r] = 1.f / sums[r];
  if (l15 == 0) {
#pragma unroll
    for (int r = 0; r < 4; ++r) zsh[wave][4 * l4 + r] = zinv[r];
  }
  __syncthreads();
  float zrow = zsh[wave][l15];  // zinv for q-row (m0 + l15)

  // ---- Pass B: recompute, write a, accumulate PV ----
  f32x4 oacc[4];
#pragma unroll
  for (int et = 0; et < 4; ++et) oacc[et] = (f32x4){0.f, 0.f, 0.f, 0.f};

  float* arow = oa + (((size_t)(b * H_ + h)) * L_ + (m0 + l15)) * S_ + 8 * l4;
  const u16* vb0 = vb + ((size_t)(b * H_ + h) * E_ + l15) * S_ + 8 * l4;
  u16* ptw = &pt[wave][0][0];

#pragma unroll 1
  for (int c2 = 0; c2 < 64; ++c2) {
#pragma unroll
    for (int cc = 0; cc < 2; ++cc) {
      int c = 2 * c2 + cc;
      const u16* kp = kbase + (size_t)c * (16 * H_ * E_);
      f32x4 acc = {0.f, 0.f, 0.f, 0.f};
      acc = __builtin_amdgcn_mfma_f32_16x16x32_bf16(qa0, *(const bf16x8*)(kp), acc, 0, 0, 0);
      acc = __builtin_amdgcn_mfma_f32_16x16x32_bf16(qa1, *(const bf16x8*)(kp + 32), acc, 0, 0, 0);
      float d = dbase[c * 16];
#pragma unroll
      for (int r = 0; r < 4; ++r) {
        float p = __builtin_amdgcn_exp2f((acc[r] + d) * LOG2E);
        ptw[(4 * l4 + r) * 40 + cc * 16 + l15] = f32_to_bf16(p);
      }
    }
    asm volatile("" ::: "memory");
    // pa fragment: row = l15, k = 8*l4+j  (this IS the PV A-fragment layout)
    bf16x8 pa = *(const bf16x8*)(ptw + l15 * 40 + 8 * l4);
    asm volatile("" ::: "memory");

    // coalesced a write: row l15, 8 consecutive s at c2*32 + 8*l4
    union { u16x4 h4; uint64_t u; } lo_u, hi_u;
    f32x4 alo, ahi;
#pragma unroll
    for (int j = 0; j < 4; ++j) {
      alo[j] = (float)pa[j] * zrow;
      ahi[j] = (float)pa[j + 4] * zrow;
    }
    *(f32x4*)(arow + (size_t)c2 * 32) = alo;
    *(f32x4*)(arow + (size_t)c2 * 32 + 4) = ahi;

    // PV: out[q, e] += p[q, s] * V'[e, s]
#pragma unroll
    for (int et = 0; et < 4; ++et) {
      bf16x8 vf = *(const bf16x8*)(vb0 + (size_t)et * 16 * S_ + c2 * 32);
      oacc[et] = __builtin_amdgcn_mfma_f32_16x16x32_bf16(pa, vf, oacc[et], 0, 0, 0);
    }
  }

  // out [B,L,H,E]: rows 4*l4+r, cols et*16+l15
#pragma unroll
  for (int et = 0; et < 4; ++et) {
#pragma unroll
    for (int r = 0; r < 4; ++r) {
      int row = 4 * l4 + r;
      out[(((size_t)b * L_ + (m0 + row)) * H_ + h) * E_ + et * 16 + l15] =
          oacc[et][r] * zinv[r];
    }
  }
}

extern "C" void kernel_launch(void* const* d_in, const int* in_sizes, int n_in,
                              void* d_out, int out_size, void* d_ws, size_t ws_size,
                              hipStream_t stream) {
  (void)in_sizes; (void)n_in; (void)out_size;
  const float* q = (const float*)d_in[0];
  const float* k = (const float*)d_in[1];
  const float* v = (const float*)d_in[2];
  const float* tau = (const float*)d_in[3];
  const float* delta = (const float*)d_in[4];
  float* out = (float*)d_out;
  float* oa = out + (size_t)B_ * L_ * H_ * E_;

  const size_t NQ = (size_t)B_ * L_ * H_ * E_;  // 4194304
  u16* qb = (u16*)d_ws;
  u16* kb = qb + NQ;
  u16* vb = kb + NQ;
  float* dl = (float*)(vb + NQ);
  size_t need = 3 * NQ * sizeof(u16) + (size_t)B_ * S_ * sizeof(float);
  if (ws_size < need) return;

  prep_qkd<<<4096, 256, 0, stream>>>(q, k, tau, delta, qb, kb, dl);
  prep_v<<<4096, 256, 0, stream>>>(v, vb);
  attn_fused<<<1024, 256, 0, stream>>>(qb, kb, vb, dl, out, oa);
}